// Round 6
// baseline (103.389 us; speedup 1.0000x reference)
//
#include <hip/hip_runtime.h>

typedef float f32x4 __attribute__((ext_vector_type(4)));
typedef _Float16 half8 __attribute__((ext_vector_type(8)));

#define NEG 0.2f

// ---------------------------------------------------------------------------
// K1: Wh = nf @ W^T (f32), s1 = Wh@a1, s2 = Wh@a2 (exact f32),
//     per-block max(s2) -> smax slots, Wh -> fp16 transposed [b][o][j].
// grid 256 = 8 batches x 32 row-blocks of 64 rows; block 256 (4 waves).
// ---------------------------------------------------------------------------
__global__ __launch_bounds__(256) void gat_wh_kernel(
    const float* __restrict__ nf, const float* __restrict__ W,
    const float* __restrict__ a, _Float16* __restrict__ whT,
    float* __restrict__ s1g, float* __restrict__ s2g, float* __restrict__ smax)
{
    const int b    = blockIdx.x >> 5;
    const int rb   = blockIdx.x & 31;
    const int row0 = rb * 64;
    const int t    = threadIdx.x;
    const int lane = t & 63;
    const int wv   = t >> 6;

    __shared__ _Float16 whL[64][72];   // [row][o], pad to 72 to spread banks
    __shared__ float    wred[4];

    // W row (o = lane) in registers: 64 VGPRs
    f32x4 Wreg[16];
    const float* wp = W + lane * 64;
#pragma unroll
    for (int i = 0; i < 16; ++i) Wreg[i] = *(const f32x4*)(wp + i * 4);
    const float a1v = a[lane];
    const float a2v = a[64 + lane];

    const float* nfb = nf + ((long)b * 2048 + row0) * 64;
    float wmax = -3.0e38f;

    for (int g = 0; g < 16; ++g) {
        const int row = g * 4 + wv;
        const f32x4* nfp = (const f32x4*)(nfb + row * 64);  // same addr across wave -> broadcast
        f32x4 acc = {0.f, 0.f, 0.f, 0.f};
#pragma unroll
        for (int i = 0; i < 16; ++i) acc += nfp[i] * Wreg[i];
        const float wh = acc.x + acc.y + acc.z + acc.w;     // Wh[row][lane]
        whL[row][lane] = (_Float16)wh;
        float p1 = wh * a1v;
        float p2 = wh * a2v;
#pragma unroll
        for (int m = 32; m >= 1; m >>= 1) {
            p1 += __shfl_xor(p1, m);
            p2 += __shfl_xor(p2, m);
        }
        if (lane == 0) {
            s1g[b * 2048 + row0 + row] = p1;
            s2g[b * 2048 + row0 + row] = p2;
            wmax = fmaxf(wmax, p2);
        }
    }
    if (lane == 0) wred[wv] = wmax;
    __syncthreads();
    if (t == 0)
        smax[blockIdx.x] = fmaxf(fmaxf(wred[0], wred[1]), fmaxf(wred[2], wred[3]));

    // transpose out: whT[(b*64+o)*2048 + row0 + j]
    const int o = t >> 2;
    const int part = t & 3;
    unsigned int tmp[8];
#pragma unroll
    for (int kk = 0; kk < 8; ++kk) {
        const int j = part * 16 + kk * 2;
        unsigned int lo = *(const unsigned short*)&whL[j][o];
        unsigned int hi = *(const unsigned short*)&whL[j + 1][o];
        tmp[kk] = lo | (hi << 16);
    }
    uint4 v0, v1;
    v0.x = tmp[0]; v0.y = tmp[1]; v0.z = tmp[2]; v0.w = tmp[3];
    v1.x = tmp[4]; v1.y = tmp[5]; v1.z = tmp[6]; v1.w = tmp[7];
    _Float16* dst = whT + ((long)(b * 64 + o) * 2048 + row0 + part * 16);
    *(uint4*)dst = v0;
    *(uint4*)(dst + 8) = v1;
}

// ---------------------------------------------------------------------------
// K1.5: denominators + rank-1 softmax tables.
//   m2_b = max_j s2; M_i = lrelu(s1_i+m2); iD_i = 1/sum_j exp(lrelu(s1_i+s2_j)-M_i)
//   UA_i = exp(s1_i - M_i)*iD_i,  UB_i = exp(0.2*s1_i - M_i)*iD_i
//   VA_j = exp(s2_j),             VB_j = exp(0.2*s2_j)
//   Then P[i][j] = (s2_j >= -s1_i) ? UA_i*VA_j : UB_i*VB_j  (exact rank-1 split)
// grid 512 = 8 batches x 64 blocks of 32 rows; block 256.
// ---------------------------------------------------------------------------
__global__ __launch_bounds__(256) void gat_denom_kernel(
    const float* __restrict__ s1g, const float* __restrict__ s2g,
    const float* __restrict__ smax, float* __restrict__ m2g,
    float* __restrict__ iDg, float* __restrict__ UAg, float* __restrict__ UBg,
    float* __restrict__ VAg, float* __restrict__ VBg)
{
    const int b  = blockIdx.x >> 6;
    const int i0 = (blockIdx.x & 63) * 32;
    const int t  = threadIdx.x;

    __shared__ __attribute__((aligned(16))) float s2sh[2048];
    __shared__ float m2sh;

#pragma unroll
    for (int k = 0; k < 8; ++k) s2sh[t + k * 256] = s2g[b * 2048 + t + k * 256];
    if (t < 32) {
        float v = smax[b * 32 + t];
#pragma unroll
        for (int m = 16; m >= 1; m >>= 1) v = fmaxf(v, __shfl_xor(v, m));
        if (t == 0) m2sh = v;
    }
    __syncthreads();

    // column tables for this block's 32-col slice
    if (t < 32) {
        const float s2c = s2sh[i0 + t];
        VAg[(b << 11) + i0 + t] = __expf(s2c);
        VBg[(b << 11) + i0 + t] = __expf(NEG * s2c);
    }

    const float m2  = m2sh;
    const int   r   = t >> 3, q = t & 7;
    const float s1r = s1g[b * 2048 + i0 + r];
    const float xm  = s1r + m2;
    const float M   = fmaxf(xm, NEG * xm);
    float acc = 0.f;
    for (int j = q; j < 2048; j += 8) {
        float x = s1r + s2sh[j];
        float e = fmaxf(x, NEG * x);
        acc += __expf(e - M);
    }
    acc += __shfl_xor(acc, 1);
    acc += __shfl_xor(acc, 2);
    acc += __shfl_xor(acc, 4);
    if (q == 0) {
        const float iD = 1.0f / acc;
        const int idx = b * 2048 + i0 + r;
        iDg[idx] = iD;
        UAg[idx] = __expf(s1r - M) * iD;
        UBg[idx] = __expf(NEG * s1r - M) * iD;
    }
    if ((blockIdx.x & 63) == 0 && t == 0) m2g[b] = m2;
}

// ---------------------------------------------------------------------------
// K2: attention store — fill-kernel clone. Plain (non-nt) dwordx4 stores,
//     monotone grid-stride sweep, ZERO exp per element (rank-1 tables).
// grid 4096 x 256; 8 iterations of one f32x4 per thread = 33.5M f32.
// ---------------------------------------------------------------------------
__global__ __launch_bounds__(256) void gat_store_kernel(
    const float* __restrict__ s1g, const float* __restrict__ s2g,
    const float* __restrict__ UAg, const float* __restrict__ UBg,
    const float* __restrict__ VAg, const float* __restrict__ VBg,
    float* __restrict__ attn)
{
    const int t = threadIdx.x;
#pragma unroll
    for (int i = 0; i < 8; ++i) {
        const int e4  = (i * 4096 + blockIdx.x) * 1024 + t * 4;  // flat f32 index
        const int b   = e4 >> 22;
        const int rb  = (b << 11) + ((e4 >> 11) & 2047);
        const int cb  = (b << 11) + (e4 & 2047);

        const float s1r = s1g[rb];   // wave-uniform (row constant across wave)
        const float ua  = UAg[rb];
        const float ub  = UBg[rb];
        const float thr = -s1r;

        f32x4 s  = *(const f32x4*)(s2g + cb);
        f32x4 va = *(const f32x4*)(VAg + cb);
        f32x4 vb = *(const f32x4*)(VBg + cb);
        f32x4 p;
#pragma unroll
        for (int e = 0; e < 4; ++e)
            p[e] = (s[e] >= thr) ? (ua * va[e]) : (ub * vb[e]);
        *(f32x4*)(attn + e4) = p;
    }
}

// ---------------------------------------------------------------------------
// K3: PV + elu (R4's validated PV role, standalone). grid 256 x 256.
//     Wave owns 16 rows x all 64 out-cols; A (P) in-register via exp,
//     B straight from L2-resident whT; 4 mfma/K-step.
// ---------------------------------------------------------------------------
__global__ __launch_bounds__(256) void gat_pv_kernel(
    const _Float16* __restrict__ whT, const float* __restrict__ s1g,
    const float* __restrict__ s2g, const float* __restrict__ m2g,
    const float* __restrict__ iDg, float* __restrict__ outp)
{
    const int t    = threadIdx.x;
    const int lane = t & 63;
    const int wv   = t >> 6;

    const int b  = blockIdx.x >> 5;
    const int i0 = (blockIdx.x & 31) * 64 + wv * 16;
    const int q  = lane & 15;
    const int g  = lane >> 4;
    const int row = i0 + q;

    const float s1r = s1g[b * 2048 + row];
    const float m2  = m2g[b];
    const float xm  = s1r + m2;
    const float Mr  = fmaxf(xm, NEG * xm);
    const float iDr = iDg[b * 2048 + row];

    const float*    s2p = s2g + b * 2048 + g * 8;
    const _Float16* B0  = whT + ((long)(b * 64 + q)) * 2048 + g * 8;

    f32x4 acc0 = {0.f,0.f,0.f,0.f}, acc1 = {0.f,0.f,0.f,0.f};
    f32x4 acc2 = {0.f,0.f,0.f,0.f}, acc3 = {0.f,0.f,0.f,0.f};

    for (int kk = 0; kk < 64; ++kk) {
        const int j0 = kk * 32;
        half8 b0 = *(const half8*)(B0 + j0);
        half8 b1 = *(const half8*)(B0 + 16 * 2048 + j0);
        half8 b2 = *(const half8*)(B0 + 32 * 2048 + j0);
        half8 b3 = *(const half8*)(B0 + 48 * 2048 + j0);

        f32x4 sa = *(const f32x4*)(s2p + j0);
        f32x4 sb = *(const f32x4*)(s2p + j0 + 4);
        half8 a;
#pragma unroll
        for (int e = 0; e < 4; ++e) {
            float x  = s1r + sa[e];
            float lr = fmaxf(x, NEG * x);
            a[e] = (_Float16)(__expf(lr - Mr) * iDr);
            float y  = s1r + sb[e];
            float lq = fmaxf(y, NEG * y);
            a[e + 4] = (_Float16)(__expf(lq - Mr) * iDr);
        }
        acc0 = __builtin_amdgcn_mfma_f32_16x16x32_f16(a, b0, acc0, 0, 0, 0);
        acc1 = __builtin_amdgcn_mfma_f32_16x16x32_f16(a, b1, acc1, 0, 0, 0);
        acc2 = __builtin_amdgcn_mfma_f32_16x16x32_f16(a, b2, acc2, 0, 0, 0);
        acc3 = __builtin_amdgcn_mfma_f32_16x16x32_f16(a, b3, acc3, 0, 0, 0);
    }

    // epilogue: elu; C/D layout col=lane&15, row=g*4+reg
    float* ob = outp + ((long)(b * 2048 + i0 + g * 4)) * 64 + q;
#pragma unroll
    for (int r = 0; r < 4; ++r) {
        float x0 = acc0[r], x1 = acc1[r], x2 = acc2[r], x3 = acc3[r];
        ob[(long)r * 64]      = (x0 > 0.f) ? x0 : (__expf(x0) - 1.0f);
        ob[(long)r * 64 + 16] = (x1 > 0.f) ? x1 : (__expf(x1) - 1.0f);
        ob[(long)r * 64 + 32] = (x2 > 0.f) ? x2 : (__expf(x2) - 1.0f);
        ob[(long)r * 64 + 48] = (x3 > 0.f) ? x3 : (__expf(x3) - 1.0f);
    }
}

extern "C" void kernel_launch(void* const* d_in, const int* in_sizes, int n_in,
                              void* d_out, int out_size, void* d_ws, size_t ws_size,
                              hipStream_t stream)
{
    (void)in_sizes; (void)n_in; (void)out_size; (void)ws_size;
    const float* nf = (const float*)d_in[0];
    const float* W  = (const float*)d_in[1];
    const float* a  = (const float*)d_in[2];
    float* outp = (float*)d_out;

    char* ws = (char*)d_ws;
    _Float16* whT = (_Float16*)ws;                     // 2 MB: [8][64][2048] fp16
    float* s1g  = (float*)(ws + 2097152);              // 64 KB
    float* s2g  = (float*)(ws + 2162688);              // 64 KB
    float* smax = (float*)(ws + 2228224);              // 1 KB (256 slots)
    float* m2g  = (float*)(ws + 2229248);              // 1 KB (8 slots)
    float* iDg  = (float*)(ws + 2230272);              // 64 KB
    float* UAg  = (float*)(ws + 2295808);              // 64 KB
    float* UBg  = (float*)(ws + 2361344);              // 64 KB
    float* VAg  = (float*)(ws + 2426880);              // 64 KB
    float* VBg  = (float*)(ws + 2492416);              // 64 KB

    gat_wh_kernel<<<256, 256, 0, stream>>>(nf, W, a, whT, s1g, s2g, smax);
    gat_denom_kernel<<<512, 256, 0, stream>>>(s1g, s2g, smax, m2g, iDg,
                                              UAg, UBg, VAg, VBg);
    gat_store_kernel<<<4096, 256, 0, stream>>>(s1g, s2g, UAg, UBg, VAg, VBg,
                                               outp + 1048576);
    gat_pv_kernel<<<256, 256, 0, stream>>>(whT, s1g, s2g, m2g, iDg, outp);
}

// Round 7
// 87.546 us; speedup vs baseline: 1.1810x; 1.1810x over previous
//
#include <hip/hip_runtime.h>

typedef float f32x4 __attribute__((ext_vector_type(4)));
typedef _Float16 half8 __attribute__((ext_vector_type(8)));

#define NEG 0.2f

// ---------------------------------------------------------------------------
// K1: Wh = nf @ W^T (f32), s1 = Wh@a1, s2 = Wh@a2 (exact f32),
//     per-block max(s2) -> smax slots, Wh -> fp16 transposed [b][o][j].
// grid 256 = 8 batches x 32 row-blocks of 64 rows; block 256 (4 waves).
// ---------------------------------------------------------------------------
__global__ __launch_bounds__(256) void gat_wh_kernel(
    const float* __restrict__ nf, const float* __restrict__ W,
    const float* __restrict__ a, _Float16* __restrict__ whT,
    float* __restrict__ s1g, float* __restrict__ s2g, float* __restrict__ smax)
{
    const int b    = blockIdx.x >> 5;
    const int rb   = blockIdx.x & 31;
    const int row0 = rb * 64;
    const int t    = threadIdx.x;
    const int lane = t & 63;
    const int wv   = t >> 6;

    __shared__ _Float16 whL[64][72];   // [row][o], pad to 72 to spread banks
    __shared__ float    wred[4];

    // W row (o = lane) in registers: 64 VGPRs
    f32x4 Wreg[16];
    const float* wp = W + lane * 64;
#pragma unroll
    for (int i = 0; i < 16; ++i) Wreg[i] = *(const f32x4*)(wp + i * 4);
    const float a1v = a[lane];
    const float a2v = a[64 + lane];

    const float* nfb = nf + ((long)b * 2048 + row0) * 64;
    float wmax = -3.0e38f;

    for (int g = 0; g < 16; ++g) {
        const int row = g * 4 + wv;
        const f32x4* nfp = (const f32x4*)(nfb + row * 64);  // same addr across wave -> broadcast
        f32x4 acc = {0.f, 0.f, 0.f, 0.f};
#pragma unroll
        for (int i = 0; i < 16; ++i) acc += nfp[i] * Wreg[i];
        const float wh = acc.x + acc.y + acc.z + acc.w;     // Wh[row][lane]
        whL[row][lane] = (_Float16)wh;
        float p1 = wh * a1v;
        float p2 = wh * a2v;
#pragma unroll
        for (int m = 32; m >= 1; m >>= 1) {
            p1 += __shfl_xor(p1, m);
            p2 += __shfl_xor(p2, m);
        }
        if (lane == 0) {
            s1g[b * 2048 + row0 + row] = p1;
            s2g[b * 2048 + row0 + row] = p2;
            wmax = fmaxf(wmax, p2);
        }
    }
    if (lane == 0) wred[wv] = wmax;
    __syncthreads();
    if (t == 0)
        smax[blockIdx.x] = fmaxf(fmaxf(wred[0], wred[1]), fmaxf(wred[2], wred[3]));

    // transpose out: whT[(b*64+o)*2048 + row0 + j]
    const int o = t >> 2;
    const int part = t & 3;
    unsigned int tmp[8];
#pragma unroll
    for (int kk = 0; kk < 8; ++kk) {
        const int j = part * 16 + kk * 2;
        unsigned int lo = *(const unsigned short*)&whL[j][o];
        unsigned int hi = *(const unsigned short*)&whL[j + 1][o];
        tmp[kk] = lo | (hi << 16);
    }
    uint4 v0, v1;
    v0.x = tmp[0]; v0.y = tmp[1]; v0.z = tmp[2]; v0.w = tmp[3];
    v1.x = tmp[4]; v1.y = tmp[5]; v1.z = tmp[6]; v1.w = tmp[7];
    _Float16* dst = whT + ((long)(b * 64 + o) * 2048 + row0 + part * 16);
    *(uint4*)dst = v0;
    *(uint4*)(dst + 8) = v1;
}

// ---------------------------------------------------------------------------
// K1.5: denominators + rank-1 softmax tables (validated in R6).
//   m2_b = max_j s2; M_i = lrelu(s1_i+m2); iD_i = 1/sum_j exp(lrelu(s1_i+s2_j)-M_i)
//   UA_i = exp(s1_i - M_i)*iD_i,  UB_i = exp(0.2*s1_i - M_i)*iD_i
//   VA_j = exp(s2_j),             VB_j = exp(0.2*s2_j)
//   P[i][j] = (s2_j >= -s1_i) ? UA_i*VA_j : UB_i*VB_j   (exact rank-1 split)
// ---------------------------------------------------------------------------
__global__ __launch_bounds__(256) void gat_denom_kernel(
    const float* __restrict__ s1g, const float* __restrict__ s2g,
    const float* __restrict__ smax, float* __restrict__ m2g,
    float* __restrict__ iDg, float* __restrict__ UAg, float* __restrict__ UBg,
    float* __restrict__ VAg, float* __restrict__ VBg)
{
    const int b  = blockIdx.x >> 6;
    const int i0 = (blockIdx.x & 63) * 32;
    const int t  = threadIdx.x;

    __shared__ __attribute__((aligned(16))) float s2sh[2048];
    __shared__ float m2sh;

#pragma unroll
    for (int k = 0; k < 8; ++k) s2sh[t + k * 256] = s2g[b * 2048 + t + k * 256];
    if (t < 32) {
        float v = smax[b * 32 + t];
#pragma unroll
        for (int m = 16; m >= 1; m >>= 1) v = fmaxf(v, __shfl_xor(v, m));
        if (t == 0) m2sh = v;
    }
    __syncthreads();

    // column tables for this block's 32-col slice
    if (t < 32) {
        const float s2c = s2sh[i0 + t];
        VAg[(b << 11) + i0 + t] = __expf(s2c);
        VBg[(b << 11) + i0 + t] = __expf(NEG * s2c);
    }

    const float m2  = m2sh;
    const int   r   = t >> 3, q = t & 7;
    const float s1r = s1g[b * 2048 + i0 + r];
    const float xm  = s1r + m2;
    const float M   = fmaxf(xm, NEG * xm);
    float acc = 0.f;
    for (int j = q; j < 2048; j += 8) {
        float x = s1r + s2sh[j];
        float e = fmaxf(x, NEG * x);
        acc += __expf(e - M);
    }
    acc += __shfl_xor(acc, 1);
    acc += __shfl_xor(acc, 2);
    acc += __shfl_xor(acc, 4);
    if (q == 0) {
        const float iD = 1.0f / acc;
        const int idx = b * 2048 + i0 + r;
        iDg[idx] = iD;
        UAg[idx] = __expf(s1r - M) * iD;
        UBg[idx] = __expf(NEG * s1r - M) * iD;
    }
    if ((blockIdx.x & 63) == 0 && t == 0) m2g[b] = m2;
}

// ---------------------------------------------------------------------------
// K2: fused roles, all store-path taxes removed.
//   blocks 0..255   (PV role): R4's validated PV (wave owns 16 rows x 64 cols,
//     A in-register via exp, B from L2-resident whT, 4 mfma/K-step).
//   blocks 256..2303 (store role): 8 rows/block. Tables (s2/VA/VB, 24KB) in
//     LDS -> ZERO global reads in the hot loop; zero exp (rank-1 cndmask);
//     PLAIN f32x4 stores (full-line coalescing in L2); no barriers after
//     staging; PV hidden under the store stream (dispatched first).
// ---------------------------------------------------------------------------
__global__ __launch_bounds__(256) void gat_main_kernel(
    const _Float16* __restrict__ whT, const float* __restrict__ s1g,
    const float* __restrict__ s2g, const float* __restrict__ m2g,
    const float* __restrict__ iDg, const float* __restrict__ UAg,
    const float* __restrict__ UBg, const float* __restrict__ VAg,
    const float* __restrict__ VBg, float* __restrict__ outp)
{
    const int t    = threadIdx.x;
    const int lane = t & 63;
    const int wv   = t >> 6;

    __shared__ __attribute__((aligned(16))) float s2sh[2048];
    __shared__ __attribute__((aligned(16))) float vash[2048];
    __shared__ __attribute__((aligned(16))) float vbsh[2048];

    if (blockIdx.x < 256) {
        // ---------------- PV role ----------------
        const int b  = blockIdx.x >> 5;
        const int i0 = (blockIdx.x & 31) * 64 + wv * 16;
        const int q  = lane & 15;
        const int g  = lane >> 4;
        const int row = i0 + q;

        const float s1r = s1g[b * 2048 + row];
        const float m2  = m2g[b];
        const float xm  = s1r + m2;
        const float Mr  = fmaxf(xm, NEG * xm);
        const float iDr = iDg[b * 2048 + row];

        const float*    s2p = s2g + b * 2048 + g * 8;
        const _Float16* B0  = whT + ((long)(b * 64 + q)) * 2048 + g * 8;

        f32x4 acc0 = {0.f,0.f,0.f,0.f}, acc1 = {0.f,0.f,0.f,0.f};
        f32x4 acc2 = {0.f,0.f,0.f,0.f}, acc3 = {0.f,0.f,0.f,0.f};

        for (int kk = 0; kk < 64; ++kk) {
            const int j0 = kk * 32;
            half8 b0 = *(const half8*)(B0 + j0);
            half8 b1 = *(const half8*)(B0 + 16 * 2048 + j0);
            half8 b2 = *(const half8*)(B0 + 32 * 2048 + j0);
            half8 b3 = *(const half8*)(B0 + 48 * 2048 + j0);

            f32x4 sa = *(const f32x4*)(s2p + j0);
            f32x4 sb = *(const f32x4*)(s2p + j0 + 4);
            half8 a;
#pragma unroll
            for (int e = 0; e < 4; ++e) {
                float x  = s1r + sa[e];
                float lr = fmaxf(x, NEG * x);
                a[e] = (_Float16)(__expf(lr - Mr) * iDr);
                float y  = s1r + sb[e];
                float lq = fmaxf(y, NEG * y);
                a[e + 4] = (_Float16)(__expf(lq - Mr) * iDr);
            }
            acc0 = __builtin_amdgcn_mfma_f32_16x16x32_f16(a, b0, acc0, 0, 0, 0);
            acc1 = __builtin_amdgcn_mfma_f32_16x16x32_f16(a, b1, acc1, 0, 0, 0);
            acc2 = __builtin_amdgcn_mfma_f32_16x16x32_f16(a, b2, acc2, 0, 0, 0);
            acc3 = __builtin_amdgcn_mfma_f32_16x16x32_f16(a, b3, acc3, 0, 0, 0);
        }

        // epilogue: elu; C/D layout col=lane&15, row=g*4+reg
        float* ob = outp + ((long)(b * 2048 + i0 + g * 4)) * 64 + q;
#pragma unroll
        for (int r = 0; r < 4; ++r) {
            float x0 = acc0[r], x1 = acc1[r], x2 = acc2[r], x3 = acc3[r];
            ob[(long)r * 64]      = (x0 > 0.f) ? x0 : (__expf(x0) - 1.0f);
            ob[(long)r * 64 + 16] = (x1 > 0.f) ? x1 : (__expf(x1) - 1.0f);
            ob[(long)r * 64 + 32] = (x2 > 0.f) ? x2 : (__expf(x2) - 1.0f);
            ob[(long)r * 64 + 48] = (x3 > 0.f) ? x3 : (__expf(x3) - 1.0f);
        }
    } else {
        // ---------------- store role ----------------
        const int sb = blockIdx.x - 256;          // 0..2047
        const int b  = sb >> 8;                   // 256 blocks per batch
        const int r0 = (sb & 255) * 8;            // 8 rows per block

        // stage tables once (only global reads in this role)
#pragma unroll
        for (int k = 0; k < 2; ++k) {
            const int idx = k * 1024 + t * 4;
            *(f32x4*)&s2sh[idx] = *(const f32x4*)(s2g + (b << 11) + idx);
            *(f32x4*)&vash[idx] = *(const f32x4*)(VAg + (b << 11) + idx);
            *(f32x4*)&vbsh[idx] = *(const f32x4*)(VBg + (b << 11) + idx);
        }
        __syncthreads();

        float* attnb = outp + 1048576 + ((long)(b * 2048 + r0)) * 2048;

#pragma unroll
        for (int r = 0; r < 8; ++r) {
            const int row  = r0 + r;
            const float s1r = s1g[(b << 11) + row];   // wave-uniform scalar
            const float ua  = UAg[(b << 11) + row];
            const float ub  = UBg[(b << 11) + row];
            const float thr = -s1r;
            float* arow = attnb + (long)r * 2048;
#pragma unroll
            for (int c = 0; c < 2; ++c) {
                const int j = c * 1024 + t * 4;
                f32x4 s  = *(const f32x4*)&s2sh[j];
                f32x4 va = *(const f32x4*)&vash[j];
                f32x4 vb = *(const f32x4*)&vbsh[j];
                f32x4 p;
#pragma unroll
                for (int e = 0; e < 4; ++e)
                    p[e] = (s[e] >= thr) ? (ua * va[e]) : (ub * vb[e]);
                *(f32x4*)(arow + j) = p;              // plain, full-line
            }
        }
    }
}

extern "C" void kernel_launch(void* const* d_in, const int* in_sizes, int n_in,
                              void* d_out, int out_size, void* d_ws, size_t ws_size,
                              hipStream_t stream)
{
    (void)in_sizes; (void)n_in; (void)out_size; (void)ws_size;
    const float* nf = (const float*)d_in[0];
    const float* W  = (const float*)d_in[1];
    const float* a  = (const float*)d_in[2];
    float* outp = (float*)d_out;

    char* ws = (char*)d_ws;
    _Float16* whT = (_Float16*)ws;                     // 2 MB: [8][64][2048] fp16
    float* s1g  = (float*)(ws + 2097152);              // 64 KB
    float* s2g  = (float*)(ws + 2162688);              // 64 KB
    float* smax = (float*)(ws + 2228224);              // 1 KB (256 slots)
    float* m2g  = (float*)(ws + 2229248);              // 1 KB (8 slots)
    float* iDg  = (float*)(ws + 2230272);              // 64 KB
    float* UAg  = (float*)(ws + 2295808);              // 64 KB
    float* UBg  = (float*)(ws + 2361344);              // 64 KB
    float* VAg  = (float*)(ws + 2426880);              // 64 KB
    float* VBg  = (float*)(ws + 2492416);              // 64 KB

    gat_wh_kernel<<<256, 256, 0, stream>>>(nf, W, a, whT, s1g, s2g, smax);
    gat_denom_kernel<<<512, 256, 0, stream>>>(s1g, s2g, smax, m2g, iDg,
                                              UAg, UBg, VAg, VBg);
    gat_main_kernel<<<2304, 256, 0, stream>>>(whT, s1g, s2g, m2g, iDg,
                                              UAg, UBg, VAg, VBg, outp);
}